// Round 3
// baseline (3994.366 us; speedup 1.0000x reference)
//
#include <hip/hip_runtime.h>

typedef unsigned short u16;
typedef unsigned int   u32;

#define BATCH   2
#define SEQ     2048
#define DMODEL  4096
#define NHEADS  32
#define NKV     8
#define HDIM    128
#define QKV_DIM 6144

typedef __bf16 bf16x8 __attribute__((ext_vector_type(8)));
typedef float  f32x4  __attribute__((ext_vector_type(4)));

__device__ __forceinline__ float b2f(u16 u) {
  u32 x = ((u32)u) << 16;
  return __builtin_bit_cast(float, x);
}
__device__ __forceinline__ u16 f2b(float f) {
  u32 x = __builtin_bit_cast(u32, f);
  x = (x + 0x7FFFu + ((x >> 16) & 1u)) >> 16;  // RNE
  return (u16)x;
}
__device__ __forceinline__ float b2f_lo(u32 p) { return __builtin_bit_cast(float, p << 16); }
__device__ __forceinline__ float b2f_hi(u32 p) { return __builtin_bit_cast(float, p & 0xFFFF0000u); }

__device__ __forceinline__ u32 pk(float a, float b) {
  return (u32)f2b(a) | ((u32)f2b(b) << 16);
}

// stage 16 contiguous elements (converting to bf16 if fp32) into LDS
__device__ __forceinline__ void stage16(const float* __restrict__ g, u16* __restrict__ lds) {
  const float4* p = (const float4*)g;
  float4 a = p[0], b = p[1], c = p[2], d = p[3];
  uint4 r0, r1;
  r0.x = pk(a.x, a.y); r0.y = pk(a.z, a.w); r0.z = pk(b.x, b.y); r0.w = pk(b.z, b.w);
  r1.x = pk(c.x, c.y); r1.y = pk(c.z, c.w); r1.z = pk(d.x, d.y); r1.w = pk(d.z, d.w);
  ((uint4*)lds)[0] = r0;
  ((uint4*)lds)[1] = r1;
}
__device__ __forceinline__ void stage16(const u16* __restrict__ g, u16* __restrict__ lds) {
  const uint4* p = (const uint4*)g;
  ((uint4*)lds)[0] = p[0];
  ((uint4*)lds)[1] = p[1];
}

// ---------------------------------------------------------------------------
// GEMM: C[m][n] = sum_k A[m][k] * W[n][k] + bias[n]   (B^T-input form)
// 128x128 block tile, 256 threads (4 waves as 2x2 of 64x64), BK=32,
// fp32->bf16 staging into LDS, mfma_f32_16x16x32_bf16, fp32 accumulate.
// MODE 0: scatter epilogue into bf16 Q/K/V [b,h,s,d]. MODE 1: fp32 C + bias.
// ---------------------------------------------------------------------------
template <int MODE, typename TA, typename TB>
__global__ __launch_bounds__(256) void gemm_bt(const TA* __restrict__ A,
                                               const TB* __restrict__ Bw,
                                               const float* __restrict__ bias,
                                               float* __restrict__ outf,
                                               u16* __restrict__ oq,
                                               u16* __restrict__ ok,
                                               u16* __restrict__ ov,
                                               int K, int N) {
  __shared__ u16 As[128 * 32];
  __shared__ u16 Bs[128 * 32];
  const int t    = threadIdx.x;
  const int lane = t & 63;
  const int wv   = t >> 6;
  const int wr   = wv >> 1, wc = wv & 1;
  const int m0   = blockIdx.y * 128, n0 = blockIdx.x * 128;

  f32x4 acc[4][4] = {};

  // staging: thread t covers tile row t>>1, cols (t&1)*16 .. +16
  const int sr = t >> 1, sc = (t & 1) * 16;
  const TA* gA = A  + (size_t)(m0 + sr) * K + sc;
  const TB* gB = Bw + (size_t)(n0 + sr) * K + sc;
  u16* lA = &As[sr * 32 + sc];
  u16* lB = &Bs[sr * 32 + sc];

  const int kq   = (lane >> 4) * 8;
  const int arow = (wr * 64 + (lane & 15)) * 32 + kq;
  const int brow = (wc * 64 + (lane & 15)) * 32 + kq;

  for (int k0 = 0; k0 < K; k0 += 32) {
    __syncthreads();
    stage16(gA + k0, lA);
    stage16(gB + k0, lB);
    __syncthreads();

    bf16x8 af[4], bfr[4];
#pragma unroll
    for (int i = 0; i < 4; i++) af[i] = *(const bf16x8*)&As[arow + i * 512];
#pragma unroll
    for (int j = 0; j < 4; j++) bfr[j] = *(const bf16x8*)&Bs[brow + j * 512];
#pragma unroll
    for (int i = 0; i < 4; i++)
#pragma unroll
      for (int j = 0; j < 4; j++)
        acc[i][j] = __builtin_amdgcn_mfma_f32_16x16x32_bf16(af[i], bfr[j], acc[i][j], 0, 0, 0);
  }

  // epilogue: C/D layout col = lane&15, row = (lane>>4)*4 + rr
  const int col = lane & 15, quad = lane >> 4;
#pragma unroll
  for (int j = 0; j < 4; j++) {
    const int gn = n0 + wc * 64 + j * 16 + col;
    const float bv = bias[gn];
#pragma unroll
    for (int i = 0; i < 4; i++) {
      const int gmb = m0 + wr * 64 + i * 16 + quad * 4;
#pragma unroll
      for (int rr = 0; rr < 4; rr++) {
        const float val = acc[i][j][rr] + bv;
        const int gm = gmb + rr;
        if (MODE == 1) {
          outf[(size_t)gm * N + gn] = val;
        } else {
          const int b = gm >> 11, s = gm & (SEQ - 1);
          const int d = gn & (HDIM - 1);
          if (gn < 4096) {                      // Q
            const int hh = gn >> 7;
            oq[((size_t)(b * NHEADS + hh) * SEQ + s) * HDIM + d] = f2b(val);
          } else if (gn < 5120) {               // K
            const int hh = (gn - 4096) >> 7;
            ok[((size_t)(b * NKV + hh) * SEQ + s) * HDIM + d] = f2b(val);
          } else {                              // V
            const int hh = (gn - 5120) >> 7;
            ov[((size_t)(b * NKV + hh) * SEQ + s) * HDIM + d] = f2b(val);
          }
        }
      }
    }
  }
}

// ---------------------------------------------------------------------------
// RoPE in place on bf16 Q [B,H,S,128] and K [B,KV,S,128]; interleaved pairs.
// cos/sin in fp32 (reference dtype is fp32 -> no rounding of cos/sin).
// ---------------------------------------------------------------------------
__global__ __launch_bounds__(256) void rope_kernel(u16* __restrict__ q, u16* __restrict__ kk,
                                                   int qrows, int totrows) {
  const int idx = blockIdx.x * 256 + threadIdx.x;
  const int row = idx >> 6;
  const int i   = idx & 63;
  if (row >= totrows) return;
  u16* base;
  int r;
  if (row < qrows) { base = q  + (size_t)row * HDIM;           r = row; }
  else             { base = kk + (size_t)(row - qrows) * HDIM; r = row - qrows; }
  const int s = r & (SEQ - 1);
  const float l2theta = 13.287712379549449f;  // log2(10000)
  const float inv = exp2f(-((float)(2 * i) * (1.0f / 128.0f)) * l2theta);
  const float ang = (float)s * inv;
  const float c  = cosf(ang);
  const float sn = sinf(ang);
  const u32 xv = *(const u32*)&base[2 * i];
  const float xr = b2f_lo(xv), xi = b2f_hi(xv);
  *(u32*)&base[2 * i] = pk(xr * c - xi * sn, xr * sn + xi * c);
}

// ---------------------------------------------------------------------------
// Causal GQA attention, vector (non-MFMA) flash style.
// Block = (16 q-rows, one (b,h)); 4 waves x 4 rows; K/V chunks of 64 staged in
// LDS (row pad +4 bf16 => only 2-way bank aliasing, free). Online softmax fp32.
// ---------------------------------------------------------------------------
__global__ __launch_bounds__(256) void attn_kernel(const u16* __restrict__ q,
                                                   const u16* __restrict__ k,
                                                   const u16* __restrict__ v,
                                                   u16* __restrict__ out) {
  __shared__ float q_lds[16 * 128];
  __shared__ u16 Ks[64 * 132];
  __shared__ u16 Vs[64 * 132];
  const int t    = threadIdx.x;
  const int lane = t & 63;
  const int w    = t >> 6;
  const int qb = blockIdx.x, h = blockIdx.y, b = blockIdx.z;
  const int m0  = qb * 16;
  const int kvh = h >> 2;  // GROUP = 4
  const u16* Kp = k + (size_t)(b * NKV + kvh) * SEQ * HDIM;
  const u16* Vp = v + (size_t)(b * NKV + kvh) * SEQ * HDIM;
  const u16* Qp = q + ((size_t)(b * NHEADS + h) * SEQ + m0) * HDIM;

  const float scale = 0.08838834764831845f;  // 1/sqrt(128)
#pragma unroll
  for (int it = 0; it < 8; it++) {
    const int f = it * 256 + t;
    q_lds[f] = b2f(Qp[f]) * scale;
  }

  float O0[4] = {0.f, 0.f, 0.f, 0.f}, O1[4] = {0.f, 0.f, 0.f, 0.f};
  float mr[4], lr[4];
#pragma unroll
  for (int r = 0; r < 4; r++) { mr[r] = -1e30f; lr[r] = 0.f; }

  const int nch = ((m0 + 15) >> 6) + 1;
  for (int kc = 0; kc < nch; kc++) {
    __syncthreads();
#pragma unroll
    for (int it = 0; it < 8; it++) {
      const int g = it * 1024 + t * 4;
      const int r = g >> 7, d = g & 127;
      *(uint2*)&Ks[r * 132 + d] = *(const uint2*)&Kp[(size_t)kc * 8192 + g];
      *(uint2*)&Vs[r * 132 + d] = *(const uint2*)&Vp[(size_t)kc * 8192 + g];
    }
    __syncthreads();
#pragma unroll
    for (int ri = 0; ri < 4; ri++) {
      const int m  = m0 + w * 4 + ri;
      const int kk = kc * 64 + lane;
      const float* qr = &q_lds[(w * 4 + ri) * 128];
      const u16* kr = &Ks[lane * 132];
      float acc = 0.f;
#pragma unroll
      for (int dd = 0; dd < 32; dd++) {
        const float4 qv = *(const float4*)&qr[dd * 4];   // LDS broadcast
        const uint2 kv2 = *(const uint2*)&kr[dd * 4];
        acc = fmaf(qv.x, b2f_lo(kv2.x), acc);
        acc = fmaf(qv.y, b2f_hi(kv2.x), acc);
        acc = fmaf(qv.z, b2f_lo(kv2.y), acc);
        acc = fmaf(qv.w, b2f_hi(kv2.y), acc);
      }
      const float sc = (kk <= m) ? acc : -1e30f;
      float cm = sc;
#pragma unroll
      for (int off = 32; off >= 1; off >>= 1) cm = fmaxf(cm, __shfl_xor(cm, off));
      const float nm = fmaxf(mr[ri], cm);
      const float p = __expf(sc - nm);      // masked lanes underflow to 0
      float ps = p;
#pragma unroll
      for (int off = 32; off >= 1; off >>= 1) ps += __shfl_xor(ps, off);
      const float fac = __expf(mr[ri] - nm);
      lr[ri] = lr[ri] * fac + ps;
      mr[ri] = nm;
      O0[ri] *= fac;
      O1[ri] *= fac;
#pragma unroll 8
      for (int j = 0; j < 64; j++) {
        const float pj = __builtin_bit_cast(float,
            __builtin_amdgcn_readlane(__builtin_bit_cast(int, p), j));
        const u32 vv = *(const u32*)&Vs[j * 132 + 2 * lane];
        O0[ri] = fmaf(pj, b2f_lo(vv), O0[ri]);
        O1[ri] = fmaf(pj, b2f_hi(vv), O1[ri]);
      }
    }
  }
#pragma unroll
  for (int ri = 0; ri < 4; ri++) {
    const int m = m0 + w * 4 + ri;
    const float inv = 1.0f / lr[ri];
    const size_t o = ((size_t)(b * SEQ + m)) * DMODEL + h * HDIM + 2 * lane;
    *(u32*)&out[o] = pk(O0[ri] * inv, O1[ri] * inv);
  }
}

// ---------------------------------------------------------------------------
extern "C" void kernel_launch(void* const* d_in, const int* in_sizes, int n_in,
                              void* d_out, int out_size, void* d_ws, size_t ws_size,
                              hipStream_t stream) {
  const float* x     = (const float*)d_in[0];
  const float* w_qkv = (const float*)d_in[1];
  const float* b_qkv = (const float*)d_in[2];
  const float* w_o   = (const float*)d_in[3];
  const float* b_o   = (const float*)d_in[4];
  float* out = (float*)d_out;

  // workspace (bf16): Q 16.78M | K 4.19M | V 4.19M | attn 16.78M elems = 84 MB
  u16* q    = (u16*)d_ws;
  u16* k    = q + (size_t)BATCH * NHEADS * SEQ * HDIM;
  u16* v    = k + (size_t)BATCH * NKV * SEQ * HDIM;
  u16* attn = v + (size_t)BATCH * NKV * SEQ * HDIM;

  const dim3 blk(256);

  // 1) QKV projection + bias, scattered into bf16 [b,h,s,d] Q/K/V
  gemm_bt<0, float, float><<<dim3(QKV_DIM / 128, (BATCH * SEQ) / 128), blk, 0, stream>>>(
      x, w_qkv, b_qkv, nullptr, q, k, v, DMODEL, QKV_DIM);

  // 2) RoPE in place on Q and K
  const int qrows = BATCH * NHEADS * SEQ;
  const int totrows = qrows + BATCH * NKV * SEQ;
  rope_kernel<<<dim3((totrows * 64) / 256), blk, 0, stream>>>(q, k, qrows, totrows);

  // 3) causal GQA attention -> attn bf16 [b,s, h*128+d]
  attn_kernel<<<dim3(SEQ / 16, NHEADS, BATCH), blk, 0, stream>>>(q, k, v, attn);

  // 4) output projection + bias -> d_out (fp32)
  gemm_bt<1, u16, float><<<dim3(DMODEL / 128, (BATCH * SEQ) / 128), blk, 0, stream>>>(
      attn, w_o, b_o, out, nullptr, nullptr, nullptr, DMODEL, DMODEL);
}

// Round 4
// 1605.295 us; speedup vs baseline: 2.4882x; 2.4882x over previous
//
#include <hip/hip_runtime.h>

typedef unsigned short u16;
typedef unsigned int   u32;

#define BATCH   2
#define SEQ     2048
#define DMODEL  4096
#define NHEADS  32
#define NKV     8
#define HDIM    128
#define QKV_DIM 6144

typedef __bf16 bf16x8 __attribute__((ext_vector_type(8)));
typedef float  f32x4  __attribute__((ext_vector_type(4)));

__device__ __forceinline__ float b2f(u16 u) {
  u32 x = ((u32)u) << 16;
  return __builtin_bit_cast(float, x);
}
__device__ __forceinline__ u16 f2b(float f) {
  u32 x = __builtin_bit_cast(u32, f);
  x = (x + 0x7FFFu + ((x >> 16) & 1u)) >> 16;  // RNE
  return (u16)x;
}
__device__ __forceinline__ float b2f_lo(u32 p) { return __builtin_bit_cast(float, p << 16); }
__device__ __forceinline__ float b2f_hi(u32 p) { return __builtin_bit_cast(float, p & 0xFFFF0000u); }

__device__ __forceinline__ u32 pk(float a, float b) {
  return (u32)f2b(a) | ((u32)f2b(b) << 16);
}

// stage 16 contiguous elements (converting to bf16 if fp32) into LDS
__device__ __forceinline__ void stage16(const float* __restrict__ g, u16* __restrict__ lds) {
  const float4* p = (const float4*)g;
  float4 a = p[0], b = p[1], c = p[2], d = p[3];
  uint4 r0, r1;
  r0.x = pk(a.x, a.y); r0.y = pk(a.z, a.w); r0.z = pk(b.x, b.y); r0.w = pk(b.z, b.w);
  r1.x = pk(c.x, c.y); r1.y = pk(c.z, c.w); r1.z = pk(d.x, d.y); r1.w = pk(d.z, d.w);
  ((uint4*)lds)[0] = r0;
  ((uint4*)lds)[1] = r1;
}
__device__ __forceinline__ void stage16(const u16* __restrict__ g, u16* __restrict__ lds) {
  const uint4* p = (const uint4*)g;
  ((uint4*)lds)[0] = p[0];
  ((uint4*)lds)[1] = p[1];
}

// ---------------------------------------------------------------------------
// GEMM: C[m][n] = sum_k A[m][k] * W[n][k] + bias[n]   (B^T-input form)
// 128x128 tile, 4 waves, BK=32, mfma_f32_16x16x32_bf16, fp32 accumulate.
// MODE 0: scatter epilogue into bf16 Q/K/V [b,h,s,d]. MODE 1: fp32 C + bias.
// ---------------------------------------------------------------------------
template <int MODE, typename TA, typename TB>
__global__ __launch_bounds__(256) void gemm_bt(const TA* __restrict__ A,
                                               const TB* __restrict__ Bw,
                                               const float* __restrict__ bias,
                                               float* __restrict__ outf,
                                               u16* __restrict__ oq,
                                               u16* __restrict__ ok,
                                               u16* __restrict__ ov,
                                               int K, int N) {
  __shared__ u16 As[128 * 32];
  __shared__ u16 Bs[128 * 32];
  const int t    = threadIdx.x;
  const int lane = t & 63;
  const int wv   = t >> 6;
  const int wr   = wv >> 1, wc = wv & 1;
  const int m0   = blockIdx.y * 128, n0 = blockIdx.x * 128;

  f32x4 acc[4][4] = {};

  const int sr = t >> 1, sc = (t & 1) * 16;
  const TA* gA = A  + (size_t)(m0 + sr) * K + sc;
  const TB* gB = Bw + (size_t)(n0 + sr) * K + sc;
  u16* lA = &As[sr * 32 + sc];
  u16* lB = &Bs[sr * 32 + sc];

  const int kq   = (lane >> 4) * 8;
  const int arow = (wr * 64 + (lane & 15)) * 32 + kq;
  const int brow = (wc * 64 + (lane & 15)) * 32 + kq;

  for (int k0 = 0; k0 < K; k0 += 32) {
    __syncthreads();
    stage16(gA + k0, lA);
    stage16(gB + k0, lB);
    __syncthreads();

    bf16x8 af[4], bfr[4];
#pragma unroll
    for (int i = 0; i < 4; i++) af[i] = *(const bf16x8*)&As[arow + i * 512];
#pragma unroll
    for (int j = 0; j < 4; j++) bfr[j] = *(const bf16x8*)&Bs[brow + j * 512];
#pragma unroll
    for (int i = 0; i < 4; i++)
#pragma unroll
      for (int j = 0; j < 4; j++)
        acc[i][j] = __builtin_amdgcn_mfma_f32_16x16x32_bf16(af[i], bfr[j], acc[i][j], 0, 0, 0);
  }

  const int col = lane & 15, quad = lane >> 4;
#pragma unroll
  for (int j = 0; j < 4; j++) {
    const int gn = n0 + wc * 64 + j * 16 + col;
    const float bv = bias[gn];
#pragma unroll
    for (int i = 0; i < 4; i++) {
      const int gmb = m0 + wr * 64 + i * 16 + quad * 4;
#pragma unroll
      for (int rr = 0; rr < 4; rr++) {
        const float val = acc[i][j][rr] + bv;
        const int gm = gmb + rr;
        if (MODE == 1) {
          outf[(size_t)gm * N + gn] = val;
        } else {
          const int b = gm >> 11, s = gm & (SEQ - 1);
          const int d = gn & (HDIM - 1);
          if (gn < 4096) {
            const int hh = gn >> 7;
            oq[((size_t)(b * NHEADS + hh) * SEQ + s) * HDIM + d] = f2b(val);
          } else if (gn < 5120) {
            const int hh = (gn - 4096) >> 7;
            ok[((size_t)(b * NKV + hh) * SEQ + s) * HDIM + d] = f2b(val);
          } else {
            const int hh = (gn - 5120) >> 7;
            ov[((size_t)(b * NKV + hh) * SEQ + s) * HDIM + d] = f2b(val);
          }
        }
      }
    }
  }
}

// ---------------------------------------------------------------------------
// RoPE in place on bf16 Q and K; cos/sin in fp32.
// ---------------------------------------------------------------------------
__global__ __launch_bounds__(256) void rope_kernel(u16* __restrict__ q, u16* __restrict__ kk,
                                                   int qrows, int totrows) {
  const int idx = blockIdx.x * 256 + threadIdx.x;
  const int row = idx >> 6;
  const int i   = idx & 63;
  if (row >= totrows) return;
  u16* base;
  int r;
  if (row < qrows) { base = q  + (size_t)row * HDIM;           r = row; }
  else             { base = kk + (size_t)(row - qrows) * HDIM; r = row - qrows; }
  const int s = r & (SEQ - 1);
  const float l2theta = 13.287712379549449f;  // log2(10000)
  const float inv = exp2f(-((float)(2 * i) * (1.0f / 128.0f)) * l2theta);
  const float ang = (float)s * inv;
  const float c  = cosf(ang);
  const float sn = sinf(ang);
  const u32 xv = *(const u32*)&base[2 * i];
  const float xr = b2f_lo(xv), xi = b2f_hi(xv);
  *(u32*)&base[2 * i] = pk(xr * c - xi * sn, xr * sn + xi * c);
}

// ---------------------------------------------------------------------------
// MFMA flash attention (causal, GQA group=4).
// Block: 128 q-rows, 4 waves x 32 rows (2 row-tiles of 16). K-chunk = 64 keys.
// S=QK^T and O=PV via mfma_f32_16x16x32_bf16; online softmax in C/D layout;
// P re-enters A-layout via per-wave LDS round-trip; V staged transposed with
// XOR group swizzle (u32-packed transpose writes).
// ---------------------------------------------------------------------------
__global__ __launch_bounds__(256) void attn_mfma(const u16* __restrict__ q,
                                                 const u16* __restrict__ k,
                                                 const u16* __restrict__ v,
                                                 u16* __restrict__ out) {
  __shared__ u16 Ks[64 * 136];       // [key][d], stride 136 u16 (272B, 16B-mult)
  __shared__ u16 VtBuf[128 * 72];    // [d][key-swizzled], stride 72 u16 (144B)
  __shared__ u16 Ps[4 * 32 * 72];    // per wave: [row][key], stride 72 u16
  u32* Vt32 = (u32*)VtBuf;           // row stride 36 u32

  const int t    = threadIdx.x;
  const int lane = t & 63;
  const int w    = t >> 6;
  const int q4   = lane >> 4, l15 = lane & 15;
  const int qb   = 15 - (int)blockIdx.x;   // heavy blocks first
  const int h = blockIdx.y, b = blockIdx.z;
  const int m0 = qb * 128;
  const int mw = m0 + w * 32;              // wave's first q-row
  const int kvh = h >> 2;
  const u16* Qp = q + (size_t)(b * NHEADS + h) * SEQ * HDIM;
  const u16* Kp = k + (size_t)(b * NKV + kvh) * SEQ * HDIM;
  const u16* Vp = v + (size_t)(b * NKV + kvh) * SEQ * HDIM;
  const float scale = 0.08838834764831845f;  // 1/sqrt(128)

  // Q fragments (held in registers for the whole kernel)
  bf16x8 qf[2][4];
#pragma unroll
  for (int rt = 0; rt < 2; rt++)
#pragma unroll
    for (int kk = 0; kk < 4; kk++)
      qf[rt][kk] = *(const bf16x8*)&Qp[(size_t)(mw + rt * 16 + l15) * HDIM + kk * 32 + q4 * 8];

  f32x4 oacc[2][8] = {};
  float mrow[2][4], lrow[2][4];
#pragma unroll
  for (int rt = 0; rt < 2; rt++)
#pragma unroll
    for (int rr = 0; rr < 4; rr++) { mrow[rt][rr] = -1e30f; lrow[rt][rr] = 0.f; }

  u16* Pw = &Ps[w * 32 * 72];

  const int nch = qb * 2 + 2;
  for (int kc = 0; kc < nch; kc++) {
    __syncthreads();
    // ---- stage K: row-major, vector 16B units, coalesced ----
#pragma unroll
    for (int i = 0; i < 4; i++) {
      const int u = t + i * 256;           // 1024 units of 16B
      const int r = u >> 4, c = (u & 15) * 8;
      *(uint4*)&Ks[r * 136 + c] = *(const uint4*)&Kp[(size_t)(kc * 64 + r) * HDIM + c];
    }
    // ---- stage V transposed: u32 key-pair packing + XOR group swizzle ----
#pragma unroll
    for (int i = 0; i < 4; i++) {
      const int tau = t + i * 256;         // 1024 tasks
      const int k2 = tau >> 5, dq = tau & 31;
      const uint2 e0 = *(const uint2*)&Vp[(size_t)(kc * 64 + 2 * k2) * HDIM + dq * 4];
      const uint2 e1 = *(const uint2*)&Vp[(size_t)(kc * 64 + 2 * k2 + 1) * HDIM + dq * 4];
      u32 wj[4];
      wj[0] = (e0.x & 0xFFFFu) | (e1.x << 16);
      wj[1] = (e0.x >> 16)     | (e1.x & 0xFFFF0000u);
      wj[2] = (e0.y & 0xFFFFu) | (e1.y << 16);
      wj[3] = (e0.y >> 16)     | (e1.y & 0xFFFF0000u);
      const int g = k2 >> 2;
#pragma unroll
      for (int j = 0; j < 4; j++) {
        const int d = dq * 4 + j;
        const int gs = g ^ ((d >> 3) & 7);
        Vt32[d * 36 + gs * 4 + (k2 & 3)] = wj[j];
      }
    }
    __syncthreads();

    if (kc * 64 <= mw + 31) {   // wave has at least one unmasked key this chunk
      // ---- S = QK^T ----
      f32x4 sacc[2][4] = {};
#pragma unroll
      for (int ct = 0; ct < 4; ct++) {
#pragma unroll
        for (int kk = 0; kk < 4; kk++) {
          const bf16x8 kb = *(const bf16x8*)&Ks[(ct * 16 + l15) * 136 + kk * 32 + q4 * 8];
          sacc[0][ct] = __builtin_amdgcn_mfma_f32_16x16x32_bf16(qf[0][kk], kb, sacc[0][ct], 0, 0, 0);
          sacc[1][ct] = __builtin_amdgcn_mfma_f32_16x16x32_bf16(qf[1][kk], kb, sacc[1][ct], 0, 0, 0);
        }
      }
      // ---- online softmax (row stats replicated across each 16-lane quad) ----
#pragma unroll
      for (int rt = 0; rt < 2; rt++) {
        float alpha[4];
        float pv[4][4];  // [ct][rr]
#pragma unroll
        for (int rr = 0; rr < 4; rr++) {
          const int mm = mw + rt * 16 + q4 * 4 + rr;
          float sv[4];
          float vmax = -1e30f;
#pragma unroll
          for (int ct = 0; ct < 4; ct++) {
            const int key = kc * 64 + ct * 16 + l15;
            float s = sacc[rt][ct][rr] * scale;
            s = (key <= mm) ? s : -1e30f;
            sv[ct] = s;
            vmax = fmaxf(vmax, s);
          }
          vmax = fmaxf(vmax, __shfl_xor(vmax, 1));
          vmax = fmaxf(vmax, __shfl_xor(vmax, 2));
          vmax = fmaxf(vmax, __shfl_xor(vmax, 4));
          vmax = fmaxf(vmax, __shfl_xor(vmax, 8));
          const float nm = fmaxf(mrow[rt][rr], vmax);
          float sum = 0.f;
#pragma unroll
          for (int ct = 0; ct < 4; ct++) {
            const float p = __expf(sv[ct] - nm);   // masked lanes underflow to 0
            pv[ct][rr] = p;
            sum += p;
          }
          sum += __shfl_xor(sum, 1);
          sum += __shfl_xor(sum, 2);
          sum += __shfl_xor(sum, 4);
          sum += __shfl_xor(sum, 8);
          const float al = __expf(mrow[rt][rr] - nm);
          alpha[rr] = al;
          mrow[rt][rr] = nm;
          lrow[rt][rr] = lrow[rt][rr] * al + sum;
        }
#pragma unroll
        for (int dt = 0; dt < 8; dt++)
#pragma unroll
          for (int rr = 0; rr < 4; rr++) oacc[rt][dt][rr] *= alpha[rr];
        // P -> per-wave LDS (row-major), scattered u16 writes
#pragma unroll
        for (int ct = 0; ct < 4; ct++)
#pragma unroll
          for (int rr = 0; rr < 4; rr++)
            Pw[(rt * 16 + q4 * 4 + rr) * 72 + ct * 16 + l15] = f2b(pv[ct][rr]);
      }
      // ---- O += P V ----
#pragma unroll
      for (int kk2 = 0; kk2 < 2; kk2++) {
        bf16x8 pa[2];
        pa[0] = *(const bf16x8*)&Pw[(l15) * 72 + kk2 * 32 + q4 * 8];
        pa[1] = *(const bf16x8*)&Pw[(16 + l15) * 72 + kk2 * 32 + q4 * 8];
#pragma unroll
        for (int dt = 0; dt < 8; dt++) {
          const int d = dt * 16 + l15;
          const int gs = (kk2 * 4 + q4) ^ ((d >> 3) & 7);
          const bf16x8 vb = *(const bf16x8*)&Vt32[d * 36 + gs * 4];
          oacc[0][dt] = __builtin_amdgcn_mfma_f32_16x16x32_bf16(pa[0], vb, oacc[0][dt], 0, 0, 0);
          oacc[1][dt] = __builtin_amdgcn_mfma_f32_16x16x32_bf16(pa[1], vb, oacc[1][dt], 0, 0, 0);
        }
      }
    }
  }

  // ---- epilogue: O / l -> attn buffer [b][s][h*128+d] ----
#pragma unroll
  for (int rt = 0; rt < 2; rt++)
#pragma unroll
    for (int rr = 0; rr < 4; rr++) {
      const float inv = 1.0f / lrow[rt][rr];
      const int mm = mw + rt * 16 + q4 * 4 + rr;
      u16* op = &out[((size_t)(b * SEQ + mm)) * DMODEL + h * HDIM + l15];
#pragma unroll
      for (int dt = 0; dt < 8; dt++)
        op[dt * 16] = f2b(oacc[rt][dt][rr] * inv);
    }
}

// ---------------------------------------------------------------------------
extern "C" void kernel_launch(void* const* d_in, const int* in_sizes, int n_in,
                              void* d_out, int out_size, void* d_ws, size_t ws_size,
                              hipStream_t stream) {
  const float* x     = (const float*)d_in[0];
  const float* w_qkv = (const float*)d_in[1];
  const float* b_qkv = (const float*)d_in[2];
  const float* w_o   = (const float*)d_in[3];
  const float* b_o   = (const float*)d_in[4];
  float* out = (float*)d_out;

  u16* q    = (u16*)d_ws;
  u16* k    = q + (size_t)BATCH * NHEADS * SEQ * HDIM;
  u16* v    = k + (size_t)BATCH * NKV * SEQ * HDIM;
  u16* attn = v + (size_t)BATCH * NKV * SEQ * HDIM;

  const dim3 blk(256);

  gemm_bt<0, float, float><<<dim3(QKV_DIM / 128, (BATCH * SEQ) / 128), blk, 0, stream>>>(
      x, w_qkv, b_qkv, nullptr, q, k, v, DMODEL, QKV_DIM);

  const int qrows = BATCH * NHEADS * SEQ;
  const int totrows = qrows + BATCH * NKV * SEQ;
  rope_kernel<<<dim3((totrows * 64) / 256), blk, 0, stream>>>(q, k, qrows, totrows);

  attn_mfma<<<dim3(SEQ / 128, NHEADS, BATCH), blk, 0, stream>>>(q, k, v, attn);

  gemm_bt<1, u16, float><<<dim3(DMODEL / 128, (BATCH * SEQ) / 128), blk, 0, stream>>>(
      attn, w_o, b_o, out, nullptr, nullptr, nullptr, DMODEL, DMODEL);
}